// Round 2
// baseline (351.740 us; speedup 1.0000x reference)
//
#include <hip/hip_runtime.h>

// RelativeSAMAttention: B=4,H=8,N=1024,DH=128. Outputs FP32: out[B,H,N,DH] ++ scores[B,H,N,N].
//
// R6: SYNC-BOUND fix (R5 counters: all pipes idle, 2 barriers/tile, 64B-segment score
// stores caused +43MB write amp / +22MB fetch-on-write).
//   - K and V^T fragments loaded DIRECTLY from L2-hot ws (16B slices match MFMA layout):
//     pass 1 is now barrier-free and LDS-free; replay needs sync only for the sP exchange.
//   - sP double-buffered (XOR-swizzled, stride 64) -> exactly 1 barrier per replay tile.
//   - Scores written cooperatively from sP: thread u -> ds_read_b64 + 4x bf2f*inv ->
//     one float4; every wave writes 4x256B full lines (no partial-line RMW).
//   - LDS 74KB->9.3KB, __launch_bounds__(512,6): target VGPR<=84, 3 blocks/CU (24 waves).
//   - XCD map: bid&7 owns 4 bh -> 2MB K+Vt stage set per XCD stays L2-resident.

typedef __attribute__((ext_vector_type(8))) short short8;
typedef __attribute__((ext_vector_type(4))) float f32x4;

#define OUT_ELEMS 4194304ull
#define WS_K      0ull           //  8388608 B bf16 K [bh][m][dh]
#define WS_VT     8388608ull     //  8388608 B bf16 V^T [bh][dh][m]
#define WS_CS     16777216ull    //      128 B fp32 cs[32]

__device__ __forceinline__ unsigned short f2bf(float f) {
    unsigned u = __builtin_bit_cast(unsigned, f);
    u += 0x7FFFu + ((u >> 16) & 1u);
    return (unsigned short)(u >> 16);
}
__device__ __forceinline__ float bf2f(unsigned short u) {
    return __builtin_bit_cast(float, (unsigned)u << 16);
}
__device__ __forceinline__ float softplus(float x) {
    return fmaxf(x, 0.f) + __logf(1.f + __expf(-fabsf(x)));
}
__device__ __forceinline__ unsigned cvt_pk_bf16(float lo, float hi) {
    unsigned r;
    asm("v_cvt_pk_bf16_f32 %0, %1, %2" : "=v"(r) : "v"(lo), "v"(hi));
    return r;
}

// ---------------- merged prep: blocks [0,512) K-convert, [512,1024) V-transpose, [1024,1056) cs ----
__global__ __launch_bounds__(256) void prep_all(
    const float* __restrict__ k, const float* __restrict__ v, const float* __restrict__ c,
    unsigned short* __restrict__ wsK, unsigned short* __restrict__ wsVt, float* __restrict__ wsCs)
{
    __shared__ unsigned short sT[64 * 132];
    const int blk = blockIdx.x, tid = threadIdx.x;
    if (blk < 512) {
        int t = blk * 256 + tid;
        for (int u = t; u < 524288; u += 131072) {
            float4 a = reinterpret_cast<const float4*>(k)[u * 2];
            float4 b = reinterpret_cast<const float4*>(k)[u * 2 + 1];
            short8 o;
            o[0]=(short)f2bf(a.x); o[1]=(short)f2bf(a.y); o[2]=(short)f2bf(a.z); o[3]=(short)f2bf(a.w);
            o[4]=(short)f2bf(b.x); o[5]=(short)f2bf(b.y); o[6]=(short)f2bf(b.z); o[7]=(short)f2bf(b.w);
            reinterpret_cast<short8*>(wsK)[u] = o;
        }
    } else if (blk < 1024) {
        const int vb = blk - 512;
        const int bh = vb >> 4, m0 = (vb & 15) * 64;
        const float* src = v + ((size_t)bh * 1024 + m0) * 128;
        for (int i = tid; i < 2048; i += 256) {
            int row = i >> 5, c4 = i & 31;
            float4 t = reinterpret_cast<const float4*>(src)[i];
            unsigned long long pk = (unsigned long long)f2bf(t.x)
                                  | ((unsigned long long)f2bf(t.y) << 16)
                                  | ((unsigned long long)f2bf(t.z) << 32)
                                  | ((unsigned long long)f2bf(t.w) << 48);
            *reinterpret_cast<unsigned long long*>(&sT[row * 132 + c4 * 4]) = pk;
        }
        __syncthreads();
        for (int u = tid; u < 2048; u += 256) {
            int dh = u >> 4, ms = u & 15;
            unsigned long long pk = (unsigned long long)sT[(ms*4+0)*132 + dh]
                                  | ((unsigned long long)sT[(ms*4+1)*132 + dh] << 16)
                                  | ((unsigned long long)sT[(ms*4+2)*132 + dh] << 32)
                                  | ((unsigned long long)sT[(ms*4+3)*132 + dh] << 48);
            *reinterpret_cast<unsigned long long*>(&wsVt[((size_t)bh * 128 + dh) * 1024 + m0 + ms * 4]) = pk;
        }
    } else {
        __shared__ float red[4];
        const int bh = blk - 1024;
        float p = 0.f;
        for (int i = tid; i < 1024; i += 256) p += softplus(c[(size_t)bh * 1024 + i]);
        p += __shfl_xor(p, 32, 64); p += __shfl_xor(p, 16, 64); p += __shfl_xor(p, 8, 64);
        p += __shfl_xor(p,  4, 64); p += __shfl_xor(p,  2, 64); p += __shfl_xor(p, 1, 64);
        if ((tid & 63) == 0) red[tid >> 6] = p;
        __syncthreads();
        if (tid == 0) wsCs[bh] = red[0] + red[1] + red[2] + red[3] + 1e-9f;
    }
}

// ---------------- main: barrier-free pass1 (direct L2 fragments) + 1-barrier replay ----------------
__global__ __launch_bounds__(512, 6) void sam_main(
    const float* __restrict__ q, const float* __restrict__ dqp, const float* __restrict__ dkp,
    const float* __restrict__ w_w, const float* __restrict__ b_w,
    const float* __restrict__ w_b, const float* __restrict__ b_b,
    const unsigned short* __restrict__ wsK, const unsigned short* __restrict__ wsVt,
    const float* __restrict__ wsCs, float* __restrict__ out)
{
    __shared__ __align__(16) unsigned short uS[4352];   // sQ[32][136] (prologue) ∪ sP[2][32][64] (replay)
    __shared__ float s_red[128];
    __shared__ float s_inv[32];

    const int bid  = blockIdx.x;
    const int xcd  = bid & 7;                 // round-robin XCD assumption (perf-only)
    const int j    = bid >> 3;                // 0..127 within XCD
    const int bh   = xcd * 4 + (j & 3);       // 4 bh per XCD -> 2 MB stage set fits L2
    const int n0   = (j >> 2) * 32;
    const int b    = bh >> 3;
    const int h    = bh & 7;
    const int tid  = threadIdx.x;
    const int lane = tid & 63;
    const int wave = tid >> 6;
    const int l15  = lane & 15;
    const int quad = lane >> 4;
    const int wr   = wave >> 2;               // row half (16 rows)
    const int wc   = wave & 3;                // col quarter (16 m) / dh quarter (32 dh)
    const int mq   = wc * 16 + l15;

    const float ww = w_w[h], bw = b_w[h], wb = w_b[h], bb = b_b[h];
    const float wwn = -ww, bwn = -bw;
    const float SCALE = 0.08838834764831845f;   // 1/sqrt(128), folded into Q

    // ---- prologue: Q rows [n0,n0+32) -> bf16 (pre-scaled) into sQ; dq geometry; cs ----
    {
        const float* qbase = q + ((size_t)bh * 1024 + n0) * 128;
        for (int i = tid; i < 1024; i += 512) {
            int row = i >> 5, c4 = i & 31;
            float4 t = reinterpret_cast<const float4*>(qbase)[i];
            unsigned long long pk = (unsigned long long)f2bf(t.x * SCALE)
                                  | ((unsigned long long)f2bf(t.y * SCALE) << 16)
                                  | ((unsigned long long)f2bf(t.z * SCALE) << 32)
                                  | ((unsigned long long)f2bf(t.w * SCALE) << 48);
            *reinterpret_cast<unsigned long long*>(&uS[row * 136 + c4 * 4]) = pk;
        }
    }
    float qxm[4], qym[4], qzm[4], qs[4];
    #pragma unroll
    for (int r = 0; r < 4; r++) {
        int nl = wr * 16 + quad * 4 + r;
        float4 d4 = reinterpret_cast<const float4*>(dqp)[(size_t)b * 1024 + n0 + nl];
        qxm[r] = -2.f * d4.x; qym[r] = -2.f * d4.y; qzm[r] = -2.f * d4.z;
        qs[r] = d4.x*d4.x + d4.y*d4.y + d4.z*d4.z;
    }
    const float cs = wsCs[bh];
    __syncthreads();
    short8 afr[4];
    {
        const unsigned short* aq = &uS[(wr * 16 + l15) * 136 + quad * 8];
        #pragma unroll
        for (int ks = 0; ks < 4; ks++)
            afr[ks] = *reinterpret_cast<const short8*>(aq + ks * 32);
    }
    __syncthreads();   // uS free: becomes sP[2]

    // ================= PASS 1: barrier-free. K fragments direct from L2-hot wsK =================
    const unsigned short* kb = wsK + ((size_t)bh * 1024 + wc * 16 + l15) * 128 + quad * 8;
    const float4* dkb = reinterpret_cast<const float4*>(dkp) + (size_t)b * 1024 + mq;
    float rs[4] = {0.f, 0.f, 0.f, 0.f};
    unsigned vreg[16][2];                     // raw-score cache: 16 tiles x 4 vals packed bf16
    #pragma unroll
    for (int t = 0; t < 16; t++) {
        f32x4 cacc = {0.f, 0.f, 0.f, 0.f};
        const unsigned short* kp = kb + t * 8192;          // 64 rows * 128 dh
        #pragma unroll
        for (int ks = 0; ks < 4; ks++) {
            short8 bfr = *reinterpret_cast<const short8*>(kp + ks * 32);
            cacc = __builtin_amdgcn_mfma_f32_16x16x32_bf16(afr[ks], bfr, cacc, 0, 0, 0);
        }
        float4 d4 = dkb[t * 64];
        float ksq = d4.x*d4.x + d4.y*d4.y + d4.z*d4.z;
        float val[4];
        #pragma unroll
        for (int r = 0; r < 4; r++) {
            float dist = qs[r] + ksq + qxm[r]*d4.x + qym[r]*d4.y + qzm[r]*d4.z;
            float aw = softplus(dist * wwn + bwn);
            float ab = dist * wb + bb;
            val[r] = fmaxf(cacc[r] * aw + ab, 0.f);
            rs[r] += val[r];
        }
        vreg[t][0] = cvt_pk_bf16(val[0], val[1]);
        vreg[t][1] = cvt_pk_bf16(val[2], val[3]);
    }

    // ---- rowsums -> invd; preload sP[0] behind the same barrier ----
    #pragma unroll
    for (int r = 0; r < 4; r++) {
        float ts = rs[r];
        ts += __shfl_xor(ts, 1, 64);
        ts += __shfl_xor(ts, 2, 64);
        ts += __shfl_xor(ts, 4, 64);
        ts += __shfl_xor(ts, 8, 64);
        if (l15 == 0) s_red[wc * 32 + wr * 16 + quad * 4 + r] = ts;
    }
    const int r0 = wr * 16 + quad * 4;
    const int q4 = (quad & 1) * 4;            // (r0+r)&7 = q4+r  (no carry, r<4)
    unsigned short* sP = uS;                  // [2][32 rows][64 cols], col ^= (row&7)<<3
    auto sp_write = [&](int buf, unsigned pv0, unsigned pv1) {
        unsigned short* pb = sP + buf * 2048;
        pb[(r0+0)*64 + (mq ^ ((q4+0) << 3))] = (unsigned short)(pv0);
        pb[(r0+1)*64 + (mq ^ ((q4+1) << 3))] = (unsigned short)(pv0 >> 16);
        pb[(r0+2)*64 + (mq ^ ((q4+2) << 3))] = (unsigned short)(pv1);
        pb[(r0+3)*64 + (mq ^ ((q4+3) << 3))] = (unsigned short)(pv1 >> 16);
    };
    sp_write(0, vreg[0][0], vreg[0][1]);
    __syncthreads();
    if (tid < 32) s_inv[tid] = 1.f / (s_red[tid] + s_red[32 + tid] + s_red[64 + tid] + s_red[96 + tid] + cs);
    __syncthreads();

    float inv4[4];
    #pragma unroll
    for (int r = 0; r < 4; r++) inv4[r] = s_inv[r0 + r];

    // ================= REPLAY: 1 barrier/tile. V^T fragments direct from L2-hot wsVt =================
    f32x4 oacc[2];
    oacc[0] = {0.f, 0.f, 0.f, 0.f};
    oacc[1] = {0.f, 0.f, 0.f, 0.f};
    const unsigned short* vb = wsVt + ((size_t)bh * 128 + wc * 32 + l15) * 1024 + quad * 8;
    const int crow = tid >> 4, cc4 = tid & 15;            // cooperative-store coords
    const int cswz = (crow & 7) << 3;
    float* scrow = out + OUT_ELEMS + ((size_t)bh << 20) + (size_t)(n0 + crow) * 1024 + cc4 * 4;
    const float cinv = s_inv[crow];
    const int prow = wr * 16 + l15;
    const int pswz = (l15 & 7) << 3;

    #pragma unroll
    for (int t = 0; t < 16; t++) {
        const int cur = t & 1;
        if (t < 15) sp_write(cur ^ 1, vreg[t + 1][0], vreg[t + 1][1]);
        {   // cooperative coalesced score store: wave writes 4x256B full lines
            unsigned long long pk = *reinterpret_cast<const unsigned long long*>(
                &sP[cur * 2048 + crow * 64 + ((cc4 * 4) ^ cswz)]);
            float4 o;
            o.x = bf2f((unsigned short)(pk      )) * cinv;
            o.y = bf2f((unsigned short)(pk >> 16)) * cinv;
            o.z = bf2f((unsigned short)(pk >> 32)) * cinv;
            o.w = bf2f((unsigned short)(pk >> 48)) * cinv;
            *reinterpret_cast<float4*>(scrow + t * 64) = o;
        }
        #pragma unroll
        for (int ks2 = 0; ks2 < 2; ks2++) {
            short8 pfr = *reinterpret_cast<const short8*>(
                &sP[cur * 2048 + prow * 64 + ((ks2 * 32 + quad * 8) ^ pswz)]);
            #pragma unroll
            for (int df = 0; df < 2; df++) {
                short8 vfr = *reinterpret_cast<const short8*>(vb + df * 16384 + t * 64 + ks2 * 32);
                oacc[df] = __builtin_amdgcn_mfma_f32_16x16x32_bf16(pfr, vfr, oacc[df], 0, 0, 0);
            }
        }
        __syncthreads();   // sP[cur] reads done; next iter overwrites it
    }

    // ---- epilogue: O = inv[row] * acc (waves own disjoint (row,dh)) ----
    {
        float* obase = out + ((size_t)bh * 1024 + n0 + r0) * 128 + wc * 32 + l15;
        #pragma unroll
        for (int df = 0; df < 2; df++)
            #pragma unroll
            for (int r = 0; r < 4; r++)
                obase[(size_t)r * 128 + df * 16] = oacc[df][r] * inv4[r];
    }
}

extern "C" void kernel_launch(void* const* d_in, const int* in_sizes, int n_in,
                              void* d_out, int out_size, void* d_ws, size_t ws_size,
                              hipStream_t stream) {
    const float* q   = (const float*)d_in[0];
    const float* k   = (const float*)d_in[1];
    const float* v   = (const float*)d_in[2];
    const float* c   = (const float*)d_in[3];
    const float* dq  = (const float*)d_in[4];
    const float* dk  = (const float*)d_in[5];
    const float* w_w = (const float*)d_in[6];
    const float* b_w = (const float*)d_in[7];
    const float* w_b = (const float*)d_in[8];
    const float* b_b = (const float*)d_in[9];
    float* out = (float*)d_out;
    char* ws = (char*)d_ws;
    unsigned short* wsK  = (unsigned short*)(ws + WS_K);
    unsigned short* wsVt = (unsigned short*)(ws + WS_VT);
    float* wsCs   = (float*)(ws + WS_CS);

    hipLaunchKernelGGL(prep_all, dim3(1056), dim3(256), 0, stream, k, v, c, wsK, wsVt, wsCs);
    hipLaunchKernelGGL(sam_main, dim3(1024), dim3(512), 0, stream,
                       q, dq, dk, w_w, b_w, w_b, b_b, wsK, wsVt, wsCs, out);
}

// Round 4
// 289.709 us; speedup vs baseline: 1.2141x; 1.2141x over previous
//
#include <hip/hip_runtime.h>

// RelativeSAMAttention: B=4,H=8,N=1024,DH=128. Outputs FP32: out[B,H,N,DH] ++ scores[B,H,N,N].
//
// R7b: R7 with compile fix (__builtin_nontemporal_store needs a clang ext-vector type,
// not HIP's float4 class -> use f32x4).
//   - async double-buffered staging via global_load_lds width=16 (no VGPR round trip),
//     1 barrier/tile (was 2): stage(t+1) issued before compute(t), drained by syncthreads.
//   - linear LDS + granule XOR swizzle (g ^= row&7, 16B granules) applied on the
//     PRE-SWIZZLED GLOBAL SOURCE (guide m173): bank-conflict-free without padding.
//   - scores: cooperative full-128B-line stores from sP (ds_read_b64 + inv scale) with
//     NONTEMPORAL hint -> no partial-line RMW, no L2 pollution from the 134MB stream.
//   - bh-major block order per XCD: concurrent blocks share ONE bh's 512KB staging set.
//   - LDS 41.6KB (sK[2] ∪ sVt[2] aliased 32KB + sP[2] 8KB) + launch_bounds(512,6)
//     -> 3 blocks/CU (24 waves), VGPR target ~80 <= 85.

typedef __attribute__((ext_vector_type(8))) short short8;
typedef __attribute__((ext_vector_type(4))) float f32x4;

#define OUT_ELEMS 4194304ull
#define WS_K      0ull           //  8388608 B bf16 K [bh][m][dh]
#define WS_VT     8388608ull     //  8388608 B bf16 V^T [bh][dh][m]
#define WS_CS     16777216ull    //      128 B fp32 cs[32]

__device__ __forceinline__ unsigned short f2bf(float f) {
    unsigned u = __builtin_bit_cast(unsigned, f);
    u += 0x7FFFu + ((u >> 16) & 1u);
    return (unsigned short)(u >> 16);
}
__device__ __forceinline__ float bf2f(unsigned short u) {
    return __builtin_bit_cast(float, (unsigned)u << 16);
}
__device__ __forceinline__ float softplus(float x) {
    return fmaxf(x, 0.f) + __logf(1.f + __expf(-fabsf(x)));
}
__device__ __forceinline__ unsigned cvt_pk_bf16(float lo, float hi) {
    unsigned r;
    asm("v_cvt_pk_bf16_f32 %0, %1, %2" : "=v"(r) : "v"(lo), "v"(hi));
    return r;
}
__device__ __forceinline__ void gl_lds16(const unsigned short* g, unsigned short* l) {
    __builtin_amdgcn_global_load_lds(
        (const __attribute__((address_space(1))) void*)g,
        (__attribute__((address_space(3))) void*)l, 16, 0, 0);
}

// ---------------- merged prep: blocks [0,512) K-convert, [512,1024) V-transpose, [1024,1056) cs ----
__global__ __launch_bounds__(256) void prep_all(
    const float* __restrict__ k, const float* __restrict__ v, const float* __restrict__ c,
    unsigned short* __restrict__ wsK, unsigned short* __restrict__ wsVt, float* __restrict__ wsCs)
{
    __shared__ unsigned short sT[64 * 132];
    const int blk = blockIdx.x, tid = threadIdx.x;
    if (blk < 512) {
        int t = blk * 256 + tid;
        for (int u = t; u < 524288; u += 131072) {
            float4 a = reinterpret_cast<const float4*>(k)[u * 2];
            float4 b = reinterpret_cast<const float4*>(k)[u * 2 + 1];
            short8 o;
            o[0]=(short)f2bf(a.x); o[1]=(short)f2bf(a.y); o[2]=(short)f2bf(a.z); o[3]=(short)f2bf(a.w);
            o[4]=(short)f2bf(b.x); o[5]=(short)f2bf(b.y); o[6]=(short)f2bf(b.z); o[7]=(short)f2bf(b.w);
            reinterpret_cast<short8*>(wsK)[u] = o;
        }
    } else if (blk < 1024) {
        const int vb = blk - 512;
        const int bh = vb >> 4, m0 = (vb & 15) * 64;
        const float* src = v + ((size_t)bh * 1024 + m0) * 128;
        for (int i = tid; i < 2048; i += 256) {
            int row = i >> 5, c4 = i & 31;
            float4 t = reinterpret_cast<const float4*>(src)[i];
            unsigned long long pk = (unsigned long long)f2bf(t.x)
                                  | ((unsigned long long)f2bf(t.y) << 16)
                                  | ((unsigned long long)f2bf(t.z) << 32)
                                  | ((unsigned long long)f2bf(t.w) << 48);
            *reinterpret_cast<unsigned long long*>(&sT[row * 132 + c4 * 4]) = pk;
        }
        __syncthreads();
        for (int u = tid; u < 2048; u += 256) {
            int dh = u >> 4, ms = u & 15;
            unsigned long long pk = (unsigned long long)sT[(ms*4+0)*132 + dh]
                                  | ((unsigned long long)sT[(ms*4+1)*132 + dh] << 16)
                                  | ((unsigned long long)sT[(ms*4+2)*132 + dh] << 32)
                                  | ((unsigned long long)sT[(ms*4+3)*132 + dh] << 48);
            *reinterpret_cast<unsigned long long*>(&wsVt[((size_t)bh * 128 + dh) * 1024 + m0 + ms * 4]) = pk;
        }
    } else {
        __shared__ float red[4];
        const int bh = blk - 1024;
        float p = 0.f;
        for (int i = tid; i < 1024; i += 256) p += softplus(c[(size_t)bh * 1024 + i]);
        p += __shfl_xor(p, 32, 64); p += __shfl_xor(p, 16, 64); p += __shfl_xor(p, 8, 64);
        p += __shfl_xor(p,  4, 64); p += __shfl_xor(p,  2, 64); p += __shfl_xor(p, 1, 64);
        if ((tid & 63) == 0) red[tid >> 6] = p;
        __syncthreads();
        if (tid == 0) wsCs[bh] = red[0] + red[1] + red[2] + red[3] + 1e-9f;
    }
}

// ---------------- main: async dbuf staging, 1 barrier/tile ----------------
__global__ __launch_bounds__(512, 6) void sam_main(
    const float* __restrict__ q, const float* __restrict__ dqp, const float* __restrict__ dkp,
    const float* __restrict__ w_w, const float* __restrict__ b_w,
    const float* __restrict__ w_b, const float* __restrict__ b_b,
    const unsigned short* __restrict__ wsK, const unsigned short* __restrict__ wsVt,
    const float* __restrict__ wsCs, float* __restrict__ out)
{
    __shared__ __align__(16) unsigned short uSh[16384];  // 32KB: sK[2][64][128] ∪ sVt[2][128][64] ∪ sQ[32][136]
    __shared__ __align__(16) unsigned short sPb[4096];   //  8KB: sP[2][32][64], granule-XOR swizzled
    __shared__ float s_red[128];
    __shared__ float s_inv[32];

    const int bid  = blockIdx.x;
    const int xcd  = bid & 7;                 // round-robin XCD assumption (perf-only)
    const int j    = bid >> 3;                // 0..127 within XCD
    const int bh   = xcd * 4 + (j >> 5);      // bh-MAJOR: concurrent blocks share one bh (512KB, L2-hot)
    const int n0   = (j & 31) * 32;
    const int b    = bh >> 3;
    const int h    = bh & 7;
    const int tid  = threadIdx.x;
    const int lane = tid & 63;
    const int wave = tid >> 6;
    const int l15  = lane & 15;
    const int quad = lane >> 4;
    const int wr   = wave >> 2;               // row half (16 rows)
    const int wc   = wave & 3;                // col quarter (16 m) / dh quarter (32 dh)
    const int mq   = wc * 16 + l15;
    const int swz3 = l15 & 7;
    const int r0   = wr * 16 + quad * 4;
    const int q4   = (quad & 1) * 4;          // (r0+r)&7 = q4+r (no carry, r<4)

    const float ww = w_w[h], bw = b_w[h], wb = w_b[h], bb = b_b[h];
    const float wwn = -ww, bwn = -bw;
    const float SCALE = 0.08838834764831845f;   // 1/sqrt(128), folded into Q

    // ---- staging geometry (loop-invariant) ----
    const unsigned short* gKbh = wsK  + (size_t)bh * 131072;
    const unsigned short* gVbh = wsVt + (size_t)bh * 131072;
    const int krow  = tid >> 4;                                 // K-stage row (i=0): 0..31
    const int koff0 = krow * 128 + (((tid & 15) ^ (krow & 7)) << 3);
    const int vdh   = tid >> 3;                                 // V-stage dh (i=0): 0..63
    const int voff0 = vdh * 1024 + (((tid & 7) ^ (vdh & 7)) << 3);
    const int ldso  = wave * 512;                               // LDS dest shorts (wave-uniform)

    auto stageK = [&](int buf, int t) {
        const unsigned short* g = gKbh + t * 8192 + koff0;
        gl_lds16(g,        &uSh[buf * 8192 + ldso]);
        gl_lds16(g + 4096, &uSh[buf * 8192 + 4096 + ldso]);     // row+32: same low3 bits
    };
    auto stageV = [&](int buf, int t) {
        const unsigned short* g = gVbh + t * 64 + voff0;
        gl_lds16(g,         &uSh[buf * 8192 + ldso]);
        gl_lds16(g + 65536, &uSh[buf * 8192 + 4096 + ldso]);    // dh+64: same low3 bits
    };

    // ---- prologue: prefetch K tile 0 into buf1; Q rows -> bf16 (pre-scaled) sQ (in buf0) ----
    stageK(1, 0);
    {
        const float* qbase = q + ((size_t)bh * 1024 + n0) * 128;
        for (int i = tid; i < 1024; i += 512) {
            int row = i >> 5, c4 = i & 31;
            float4 t = reinterpret_cast<const float4*>(qbase)[i];
            unsigned long long pk = (unsigned long long)f2bf(t.x * SCALE)
                                  | ((unsigned long long)f2bf(t.y * SCALE) << 16)
                                  | ((unsigned long long)f2bf(t.z * SCALE) << 32)
                                  | ((unsigned long long)f2bf(t.w * SCALE) << 48);
            *reinterpret_cast<unsigned long long*>(&uSh[row * 136 + c4 * 4]) = pk;
        }
    }
    float qxm[4], qym[4], qzm[4], qs[4];
    #pragma unroll
    for (int r = 0; r < 4; r++) {
        float4 d4 = reinterpret_cast<const float4*>(dqp)[(size_t)b * 1024 + n0 + r0 + r];
        qxm[r] = -2.f * d4.x; qym[r] = -2.f * d4.y; qzm[r] = -2.f * d4.z;
        qs[r] = d4.x*d4.x + d4.y*d4.y + d4.z*d4.z;
    }
    const float cs = wsCs[bh];
    __syncthreads();                           // sQ visible; stage(buf1,t0) drained
    short8 afr[4];
    {
        const unsigned short* aq = &uSh[(wr * 16 + l15) * 136 + quad * 8];
        #pragma unroll
        for (int ks = 0; ks < 4; ks++)
            afr[ks] = *reinterpret_cast<const short8*>(aq + ks * 32);
    }
    __syncthreads();                           // all afr reads done; buf0 free

    const float4* dkb = reinterpret_cast<const float4*>(dkp) + (size_t)b * 1024 + mq;

    // ================= PASS 1: 1 barrier/tile, staging overlapped =================
    float rs[4] = {0.f, 0.f, 0.f, 0.f};
    unsigned vreg[16][2];                      // raw-score cache: 16 tiles x 4 vals packed bf16
    #pragma unroll
    for (int t = 0; t < 16; t++) {
        const int bswz = (1 ^ (t & 1)) * 8192; // read buf: t0->1, t1->0, ...
        if (t < 15) stageK(t & 1, t + 1);      // async prefetch next tile
        f32x4 cacc = {0.f, 0.f, 0.f, 0.f};
        const unsigned short* bq = &uSh[bswz + mq * 128];
        #pragma unroll
        for (int ks = 0; ks < 4; ks++) {
            short8 bfr = *reinterpret_cast<const short8*>(bq + (((ks * 4 + quad) ^ swz3) << 3));
            cacc = __builtin_amdgcn_mfma_f32_16x16x32_bf16(afr[ks], bfr, cacc, 0, 0, 0);
        }
        float4 d4 = dkb[t * 64];
        float ksq = d4.x*d4.x + d4.y*d4.y + d4.z*d4.z;
        float val[4];
        #pragma unroll
        for (int r = 0; r < 4; r++) {
            float dist = qs[r] + ksq + qxm[r]*d4.x + qym[r]*d4.y + qzm[r]*d4.z;
            float aw = softplus(dist * wwn + bwn);
            float ab = dist * wb + bb;
            val[r] = fmaxf(cacc[r] * aw + ab, 0.f);
            rs[r] += val[r];
        }
        vreg[t][0] = cvt_pk_bf16(val[0], val[1]);
        vreg[t][1] = cvt_pk_bf16(val[2], val[3]);
        __syncthreads();                       // cur-buf reads done + next stage landed
    }

    // ---- rowsums -> invd; prefetch V tile 0 + sP[0] behind the same barriers ----
    #pragma unroll
    for (int r = 0; r < 4; r++) {
        float ts = rs[r];
        ts += __shfl_xor(ts, 1, 64);
        ts += __shfl_xor(ts, 2, 64);
        ts += __shfl_xor(ts, 4, 64);
        ts += __shfl_xor(ts, 8, 64);
        if (l15 == 0) s_red[wc * 32 + r0 + r] = ts;
    }
    auto sp_write = [&](int buf, unsigned pv0, unsigned pv1) {
        unsigned short* pb = sPb + buf * 2048;
        const int gm = mq >> 3, c7 = mq & 7;
        pb[(r0 + 0) * 64 + (((gm ^ (q4 + 0)) << 3) | c7)] = (unsigned short)(pv0);
        pb[(r0 + 1) * 64 + (((gm ^ (q4 + 1)) << 3) | c7)] = (unsigned short)(pv0 >> 16);
        pb[(r0 + 2) * 64 + (((gm ^ (q4 + 2)) << 3) | c7)] = (unsigned short)(pv1);
        pb[(r0 + 3) * 64 + (((gm ^ (q4 + 3)) << 3) | c7)] = (unsigned short)(pv1 >> 16);
    };
    stageV(0, 0);                              // pass1's last read buf was 0; safe after its barrier
    sp_write(0, vreg[0][0], vreg[0][1]);
    __syncthreads();
    if (tid < 32) s_inv[tid] = 1.f / (s_red[tid] + s_red[32 + tid] + s_red[64 + tid] + s_red[96 + tid] + cs);
    __syncthreads();

    float inv4[4];
    #pragma unroll
    for (int r = 0; r < 4; r++) inv4[r] = s_inv[r0 + r];

    // ================= REPLAY: 1 barrier/tile; coop NT score store + PV =================
    f32x4 oacc[2];
    oacc[0] = {0.f, 0.f, 0.f, 0.f};
    oacc[1] = {0.f, 0.f, 0.f, 0.f};
    const int crow = tid >> 4, cc4 = tid & 15;             // cooperative-store coords
    const int cidx = crow * 64 + ((((cc4 >> 1) ^ (crow & 7)) << 3) | ((cc4 & 1) << 2));
    float* scrow = out + OUT_ELEMS + ((size_t)bh << 20) + (size_t)(n0 + crow) * 1024 + cc4 * 4;
    const float cinv = s_inv[crow];
    const int prow = wr * 16 + l15;

    #pragma unroll
    for (int t = 0; t < 16; t++) {
        const int bb2 = t & 1;
        if (t < 15) {
            stageV(bb2 ^ 1, t + 1);
            sp_write(bb2 ^ 1, vreg[t + 1][0], vreg[t + 1][1]);
        }
        {   // cooperative coalesced score store: full 128B lines, nontemporal
            unsigned long long pk = *reinterpret_cast<const unsigned long long*>(&sPb[bb2 * 2048 + cidx]);
            f32x4 o;
            o[0] = bf2f((unsigned short)(pk      )) * cinv;
            o[1] = bf2f((unsigned short)(pk >> 16)) * cinv;
            o[2] = bf2f((unsigned short)(pk >> 32)) * cinv;
            o[3] = bf2f((unsigned short)(pk >> 48)) * cinv;
            __builtin_nontemporal_store(o, reinterpret_cast<f32x4*>(scrow + t * 64));
        }
        #pragma unroll
        for (int ks2 = 0; ks2 < 2; ks2++) {
            short8 pfr = *reinterpret_cast<const short8*>(
                &sPb[bb2 * 2048 + prow * 64 + (((ks2 * 4 + quad) ^ swz3) << 3)]);
            #pragma unroll
            for (int df = 0; df < 2; df++) {
                const int dh = wc * 32 + df * 16 + l15;
                short8 vfr = *reinterpret_cast<const short8*>(
                    &uSh[bb2 * 8192 + dh * 64 + (((ks2 * 4 + quad) ^ swz3) << 3)]);
                oacc[df] = __builtin_amdgcn_mfma_f32_16x16x32_bf16(pfr, vfr, oacc[df], 0, 0, 0);
            }
        }
        if (t < 15) __syncthreads();           // cur reads done before next overwrites
    }

    // ---- epilogue: O = inv[row] * acc (waves own disjoint (row,dh)) ----
    {
        float* obase = out + ((size_t)bh * 1024 + n0 + r0) * 128 + wc * 32 + l15;
        #pragma unroll
        for (int df = 0; df < 2; df++)
            #pragma unroll
            for (int r = 0; r < 4; r++)
                obase[(size_t)r * 128 + df * 16] = oacc[df][r] * inv4[r];
    }
}

extern "C" void kernel_launch(void* const* d_in, const int* in_sizes, int n_in,
                              void* d_out, int out_size, void* d_ws, size_t ws_size,
                              hipStream_t stream) {
    const float* q   = (const float*)d_in[0];
    const float* k   = (const float*)d_in[1];
    const float* v   = (const float*)d_in[2];
    const float* c   = (const float*)d_in[3];
    const float* dq  = (const float*)d_in[4];
    const float* dk  = (const float*)d_in[5];
    const float* w_w = (const float*)d_in[6];
    const float* b_w = (const float*)d_in[7];
    const float* w_b = (const float*)d_in[8];
    const float* b_b = (const float*)d_in[9];
    float* out = (float*)d_out;
    char* ws = (char*)d_ws;
    unsigned short* wsK  = (unsigned short*)(ws + WS_K);
    unsigned short* wsVt = (unsigned short*)(ws + WS_VT);
    float* wsCs   = (float*)(ws + WS_CS);

    hipLaunchKernelGGL(prep_all, dim3(1056), dim3(256), 0, stream, k, v, c, wsK, wsVt, wsCs);
    hipLaunchKernelGGL(sam_main, dim3(1024), dim3(512), 0, stream,
                       q, dq, dk, w_w, b_w, w_b, b_b, wsK, wsVt, wsCs, out);
}

// Round 5
// 258.347 us; speedup vs baseline: 1.3615x; 1.1214x over previous
//
#include <hip/hip_runtime.h>

// RelativeSAMAttention: B=4,H=8,N=1024,DH=128. Outputs FP32: out[B,H,N,DH] ++ scores[B,H,N,N].
//
// R8: R7b with the spill fixed. R6/R7b both had VGPR_Count=40 under launch_bounds(512,6)
// (~85-reg cap) -> the 32-VGPR bf16 score cache spilled to scratch (+27MB fetch, +78MB
// write vs R5 = spill store+reload). Revert to launch_bounds(512,4) (128-reg cap,
// 2 blocks/CU) and keep the R7 structural wins:
//   - async double-buffered staging via global_load_lds width=16, 1 barrier/tile.
//   - linear LDS + 16B-granule XOR swizzle applied on the PRE-SWIZZLED GLOBAL SOURCE.
//   - scores: cooperative full-128B-line nontemporal stores from sP (no partial-line RMW,
//     no L2 pollution from the 134MB stream).
//   - bh-major block order per XCD: concurrent blocks share ONE bh's 512KB staging set.

typedef __attribute__((ext_vector_type(8))) short short8;
typedef __attribute__((ext_vector_type(4))) float f32x4;

#define OUT_ELEMS 4194304ull
#define WS_K      0ull           //  8388608 B bf16 K [bh][m][dh]
#define WS_VT     8388608ull     //  8388608 B bf16 V^T [bh][dh][m]
#define WS_CS     16777216ull    //      128 B fp32 cs[32]

__device__ __forceinline__ unsigned short f2bf(float f) {
    unsigned u = __builtin_bit_cast(unsigned, f);
    u += 0x7FFFu + ((u >> 16) & 1u);
    return (unsigned short)(u >> 16);
}
__device__ __forceinline__ float bf2f(unsigned short u) {
    return __builtin_bit_cast(float, (unsigned)u << 16);
}
__device__ __forceinline__ float softplus(float x) {
    return fmaxf(x, 0.f) + __logf(1.f + __expf(-fabsf(x)));
}
__device__ __forceinline__ unsigned cvt_pk_bf16(float lo, float hi) {
    unsigned r;
    asm("v_cvt_pk_bf16_f32 %0, %1, %2" : "=v"(r) : "v"(lo), "v"(hi));
    return r;
}
__device__ __forceinline__ void gl_lds16(const unsigned short* g, unsigned short* l) {
    __builtin_amdgcn_global_load_lds(
        (const __attribute__((address_space(1))) void*)g,
        (__attribute__((address_space(3))) void*)l, 16, 0, 0);
}

// ---------------- merged prep: blocks [0,512) K-convert, [512,1024) V-transpose, [1024,1056) cs ----
__global__ __launch_bounds__(256) void prep_all(
    const float* __restrict__ k, const float* __restrict__ v, const float* __restrict__ c,
    unsigned short* __restrict__ wsK, unsigned short* __restrict__ wsVt, float* __restrict__ wsCs)
{
    __shared__ unsigned short sT[64 * 132];
    const int blk = blockIdx.x, tid = threadIdx.x;
    if (blk < 512) {
        int t = blk * 256 + tid;
        for (int u = t; u < 524288; u += 131072) {
            float4 a = reinterpret_cast<const float4*>(k)[u * 2];
            float4 b = reinterpret_cast<const float4*>(k)[u * 2 + 1];
            short8 o;
            o[0]=(short)f2bf(a.x); o[1]=(short)f2bf(a.y); o[2]=(short)f2bf(a.z); o[3]=(short)f2bf(a.w);
            o[4]=(short)f2bf(b.x); o[5]=(short)f2bf(b.y); o[6]=(short)f2bf(b.z); o[7]=(short)f2bf(b.w);
            reinterpret_cast<short8*>(wsK)[u] = o;
        }
    } else if (blk < 1024) {
        const int vb = blk - 512;
        const int bh = vb >> 4, m0 = (vb & 15) * 64;
        const float* src = v + ((size_t)bh * 1024 + m0) * 128;
        for (int i = tid; i < 2048; i += 256) {
            int row = i >> 5, c4 = i & 31;
            float4 t = reinterpret_cast<const float4*>(src)[i];
            unsigned long long pk = (unsigned long long)f2bf(t.x)
                                  | ((unsigned long long)f2bf(t.y) << 16)
                                  | ((unsigned long long)f2bf(t.z) << 32)
                                  | ((unsigned long long)f2bf(t.w) << 48);
            *reinterpret_cast<unsigned long long*>(&sT[row * 132 + c4 * 4]) = pk;
        }
        __syncthreads();
        for (int u = tid; u < 2048; u += 256) {
            int dh = u >> 4, ms = u & 15;
            unsigned long long pk = (unsigned long long)sT[(ms*4+0)*132 + dh]
                                  | ((unsigned long long)sT[(ms*4+1)*132 + dh] << 16)
                                  | ((unsigned long long)sT[(ms*4+2)*132 + dh] << 32)
                                  | ((unsigned long long)sT[(ms*4+3)*132 + dh] << 48);
            *reinterpret_cast<unsigned long long*>(&wsVt[((size_t)bh * 128 + dh) * 1024 + m0 + ms * 4]) = pk;
        }
    } else {
        __shared__ float red[4];
        const int bh = blk - 1024;
        float p = 0.f;
        for (int i = tid; i < 1024; i += 256) p += softplus(c[(size_t)bh * 1024 + i]);
        p += __shfl_xor(p, 32, 64); p += __shfl_xor(p, 16, 64); p += __shfl_xor(p, 8, 64);
        p += __shfl_xor(p,  4, 64); p += __shfl_xor(p,  2, 64); p += __shfl_xor(p, 1, 64);
        if ((tid & 63) == 0) red[tid >> 6] = p;
        __syncthreads();
        if (tid == 0) wsCs[bh] = red[0] + red[1] + red[2] + red[3] + 1e-9f;
    }
}

// ---------------- main: async dbuf staging, 1 barrier/tile, no spill ----------------
__global__ __launch_bounds__(512, 4) void sam_main(
    const float* __restrict__ q, const float* __restrict__ dqp, const float* __restrict__ dkp,
    const float* __restrict__ w_w, const float* __restrict__ b_w,
    const float* __restrict__ w_b, const float* __restrict__ b_b,
    const unsigned short* __restrict__ wsK, const unsigned short* __restrict__ wsVt,
    const float* __restrict__ wsCs, float* __restrict__ out)
{
    __shared__ __align__(16) unsigned short uSh[16384];  // 32KB: sK[2][64][128] ∪ sVt[2][128][64] ∪ sQ[32][136]
    __shared__ __align__(16) unsigned short sPb[4096];   //  8KB: sP[2][32][64], granule-XOR swizzled
    __shared__ float s_red[128];
    __shared__ float s_inv[32];

    const int bid  = blockIdx.x;
    const int xcd  = bid & 7;                 // round-robin XCD assumption (perf-only)
    const int j    = bid >> 3;                // 0..127 within XCD
    const int bh   = xcd * 4 + (j >> 5);      // bh-MAJOR: concurrent blocks share one bh (512KB, L2-hot)
    const int n0   = (j & 31) * 32;
    const int b    = bh >> 3;
    const int h    = bh & 7;
    const int tid  = threadIdx.x;
    const int lane = tid & 63;
    const int wave = tid >> 6;
    const int l15  = lane & 15;
    const int quad = lane >> 4;
    const int wr   = wave >> 2;               // row half (16 rows)
    const int wc   = wave & 3;                // col quarter (16 m) / dh quarter (32 dh)
    const int mq   = wc * 16 + l15;
    const int swz3 = l15 & 7;
    const int r0   = wr * 16 + quad * 4;
    const int q4   = (quad & 1) * 4;          // (r0+r)&7 = q4+r (no carry, r<4)

    const float ww = w_w[h], bw = b_w[h], wb = w_b[h], bb = b_b[h];
    const float wwn = -ww, bwn = -bw;
    const float SCALE = 0.08838834764831845f;   // 1/sqrt(128), folded into Q

    // ---- staging geometry (loop-invariant) ----
    const unsigned short* gKbh = wsK  + (size_t)bh * 131072;
    const unsigned short* gVbh = wsVt + (size_t)bh * 131072;
    const int krow  = tid >> 4;                                 // K-stage row (i=0): 0..31
    const int koff0 = krow * 128 + (((tid & 15) ^ (krow & 7)) << 3);
    const int vdh   = tid >> 3;                                 // V-stage dh (i=0): 0..63
    const int voff0 = vdh * 1024 + (((tid & 7) ^ (vdh & 7)) << 3);
    const int ldso  = wave * 512;                               // LDS dest shorts (wave-uniform)

    auto stageK = [&](int buf, int t) {
        const unsigned short* g = gKbh + t * 8192 + koff0;
        gl_lds16(g,        &uSh[buf * 8192 + ldso]);
        gl_lds16(g + 4096, &uSh[buf * 8192 + 4096 + ldso]);     // row+32: same low3 bits
    };
    auto stageV = [&](int buf, int t) {
        const unsigned short* g = gVbh + t * 64 + voff0;
        gl_lds16(g,         &uSh[buf * 8192 + ldso]);
        gl_lds16(g + 65536, &uSh[buf * 8192 + 4096 + ldso]);    // dh+64: same low3 bits
    };

    // ---- prologue: prefetch K tile 0 into buf1; Q rows -> bf16 (pre-scaled) sQ (in buf0) ----
    stageK(1, 0);
    {
        const float* qbase = q + ((size_t)bh * 1024 + n0) * 128;
        for (int i = tid; i < 1024; i += 512) {
            int row = i >> 5, c4 = i & 31;
            float4 t = reinterpret_cast<const float4*>(qbase)[i];
            unsigned long long pk = (unsigned long long)f2bf(t.x * SCALE)
                                  | ((unsigned long long)f2bf(t.y * SCALE) << 16)
                                  | ((unsigned long long)f2bf(t.z * SCALE) << 32)
                                  | ((unsigned long long)f2bf(t.w * SCALE) << 48);
            *reinterpret_cast<unsigned long long*>(&uSh[row * 136 + c4 * 4]) = pk;
        }
    }
    float qxm[4], qym[4], qzm[4], qs[4];
    #pragma unroll
    for (int r = 0; r < 4; r++) {
        float4 d4 = reinterpret_cast<const float4*>(dqp)[(size_t)b * 1024 + n0 + r0 + r];
        qxm[r] = -2.f * d4.x; qym[r] = -2.f * d4.y; qzm[r] = -2.f * d4.z;
        qs[r] = d4.x*d4.x + d4.y*d4.y + d4.z*d4.z;
    }
    const float cs = wsCs[bh];
    __syncthreads();                           // sQ visible; stage(buf1,t0) drained
    short8 afr[4];
    {
        const unsigned short* aq = &uSh[(wr * 16 + l15) * 136 + quad * 8];
        #pragma unroll
        for (int ks = 0; ks < 4; ks++)
            afr[ks] = *reinterpret_cast<const short8*>(aq + ks * 32);
    }
    __syncthreads();                           // all afr reads done; buf0 free

    const float4* dkb = reinterpret_cast<const float4*>(dkp) + (size_t)b * 1024 + mq;

    // ================= PASS 1: 1 barrier/tile, staging overlapped =================
    float rs[4] = {0.f, 0.f, 0.f, 0.f};
    unsigned vreg[16][2];                      // raw-score cache: 16 tiles x 4 vals packed bf16
    #pragma unroll
    for (int t = 0; t < 16; t++) {
        const int bswz = (1 ^ (t & 1)) * 8192; // read buf: t0->1, t1->0, ...
        if (t < 15) stageK(t & 1, t + 1);      // async prefetch next tile
        f32x4 cacc = {0.f, 0.f, 0.f, 0.f};
        const unsigned short* bq = &uSh[bswz + mq * 128];
        #pragma unroll
        for (int ks = 0; ks < 4; ks++) {
            short8 bfr = *reinterpret_cast<const short8*>(bq + (((ks * 4 + quad) ^ swz3) << 3));
            cacc = __builtin_amdgcn_mfma_f32_16x16x32_bf16(afr[ks], bfr, cacc, 0, 0, 0);
        }
        float4 d4 = dkb[t * 64];
        float ksq = d4.x*d4.x + d4.y*d4.y + d4.z*d4.z;
        float val[4];
        #pragma unroll
        for (int r = 0; r < 4; r++) {
            float dist = qs[r] + ksq + qxm[r]*d4.x + qym[r]*d4.y + qzm[r]*d4.z;
            float aw = softplus(dist * wwn + bwn);
            float ab = dist * wb + bb;
            val[r] = fmaxf(cacc[r] * aw + ab, 0.f);
            rs[r] += val[r];
        }
        vreg[t][0] = cvt_pk_bf16(val[0], val[1]);
        vreg[t][1] = cvt_pk_bf16(val[2], val[3]);
        __syncthreads();                       // cur-buf reads done + next stage landed
    }

    // ---- rowsums -> invd; prefetch V tile 0 + sP[0] behind the same barriers ----
    #pragma unroll
    for (int r = 0; r < 4; r++) {
        float ts = rs[r];
        ts += __shfl_xor(ts, 1, 64);
        ts += __shfl_xor(ts, 2, 64);
        ts += __shfl_xor(ts, 4, 64);
        ts += __shfl_xor(ts, 8, 64);
        if (l15 == 0) s_red[wc * 32 + r0 + r] = ts;
    }
    auto sp_write = [&](int buf, unsigned pv0, unsigned pv1) {
        unsigned short* pb = sPb + buf * 2048;
        const int gm = mq >> 3, c7 = mq & 7;
        pb[(r0 + 0) * 64 + (((gm ^ (q4 + 0)) << 3) | c7)] = (unsigned short)(pv0);
        pb[(r0 + 1) * 64 + (((gm ^ (q4 + 1)) << 3) | c7)] = (unsigned short)(pv0 >> 16);
        pb[(r0 + 2) * 64 + (((gm ^ (q4 + 2)) << 3) | c7)] = (unsigned short)(pv1);
        pb[(r0 + 3) * 64 + (((gm ^ (q4 + 3)) << 3) | c7)] = (unsigned short)(pv1 >> 16);
    };
    stageV(0, 0);                              // pass1's last read buf was 0; safe after its barrier
    sp_write(0, vreg[0][0], vreg[0][1]);
    __syncthreads();
    if (tid < 32) s_inv[tid] = 1.f / (s_red[tid] + s_red[32 + tid] + s_red[64 + tid] + s_red[96 + tid] + cs);
    __syncthreads();

    float inv4[4];
    #pragma unroll
    for (int r = 0; r < 4; r++) inv4[r] = s_inv[r0 + r];

    // ================= REPLAY: 1 barrier/tile; coop NT score store + PV =================
    f32x4 oacc[2];
    oacc[0] = {0.f, 0.f, 0.f, 0.f};
    oacc[1] = {0.f, 0.f, 0.f, 0.f};
    const int crow = tid >> 4, cc4 = tid & 15;             // cooperative-store coords
    const int cidx = crow * 64 + ((((cc4 >> 1) ^ (crow & 7)) << 3) | ((cc4 & 1) << 2));
    float* scrow = out + OUT_ELEMS + ((size_t)bh << 20) + (size_t)(n0 + crow) * 1024 + cc4 * 4;
    const float cinv = s_inv[crow];
    const int prow = wr * 16 + l15;

    #pragma unroll
    for (int t = 0; t < 16; t++) {
        const int bb2 = t & 1;
        if (t < 15) {
            stageV(bb2 ^ 1, t + 1);
            sp_write(bb2 ^ 1, vreg[t + 1][0], vreg[t + 1][1]);
        }
        {   // cooperative coalesced score store: full 128B lines, nontemporal
            unsigned long long pk = *reinterpret_cast<const unsigned long long*>(&sPb[bb2 * 2048 + cidx]);
            f32x4 o;
            o[0] = bf2f((unsigned short)(pk      )) * cinv;
            o[1] = bf2f((unsigned short)(pk >> 16)) * cinv;
            o[2] = bf2f((unsigned short)(pk >> 32)) * cinv;
            o[3] = bf2f((unsigned short)(pk >> 48)) * cinv;
            __builtin_nontemporal_store(o, reinterpret_cast<f32x4*>(scrow + t * 64));
        }
        #pragma unroll
        for (int ks2 = 0; ks2 < 2; ks2++) {
            short8 pfr = *reinterpret_cast<const short8*>(
                &sPb[bb2 * 2048 + prow * 64 + (((ks2 * 4 + quad) ^ swz3) << 3)]);
            #pragma unroll
            for (int df = 0; df < 2; df++) {
                const int dh = wc * 32 + df * 16 + l15;
                short8 vfr = *reinterpret_cast<const short8*>(
                    &uSh[bb2 * 8192 + dh * 64 + (((ks2 * 4 + quad) ^ swz3) << 3)]);
                oacc[df] = __builtin_amdgcn_mfma_f32_16x16x32_bf16(pfr, vfr, oacc[df], 0, 0, 0);
            }
        }
        if (t < 15) __syncthreads();           // cur reads done before next overwrites
    }

    // ---- epilogue: O = inv[row] * acc (waves own disjoint (row,dh)) ----
    {
        float* obase = out + ((size_t)bh * 1024 + n0 + r0) * 128 + wc * 32 + l15;
        #pragma unroll
        for (int df = 0; df < 2; df++)
            #pragma unroll
            for (int r = 0; r < 4; r++)
                obase[(size_t)r * 128 + df * 16] = oacc[df][r] * inv4[r];
    }
}

extern "C" void kernel_launch(void* const* d_in, const int* in_sizes, int n_in,
                              void* d_out, int out_size, void* d_ws, size_t ws_size,
                              hipStream_t stream) {
    const float* q   = (const float*)d_in[0];
    const float* k   = (const float*)d_in[1];
    const float* v   = (const float*)d_in[2];
    const float* c   = (const float*)d_in[3];
    const float* dq  = (const float*)d_in[4];
    const float* dk  = (const float*)d_in[5];
    const float* w_w = (const float*)d_in[6];
    const float* b_w = (const float*)d_in[7];
    const float* w_b = (const float*)d_in[8];
    const float* b_b = (const float*)d_in[9];
    float* out = (float*)d_out;
    char* ws = (char*)d_ws;
    unsigned short* wsK  = (unsigned short*)(ws + WS_K);
    unsigned short* wsVt = (unsigned short*)(ws + WS_VT);
    float* wsCs   = (float*)(ws + WS_CS);

    hipLaunchKernelGGL(prep_all, dim3(1056), dim3(256), 0, stream, k, v, c, wsK, wsVt, wsCs);
    hipLaunchKernelGGL(sam_main, dim3(1024), dim3(512), 0, stream,
                       q, dq, dk, w_w, b_w, w_b, b_b, wsK, wsVt, wsCs, out);
}